// Round 6
// baseline (667.432 us; speedup 1.0000x reference)
//
#include <hip/hip_runtime.h>

// ---------------------------------------------------------------------------
// LSTMGRUHybrid: B=512, T=512, D=128, H=128 (4H=512), G=128 (3G=384), F=160, C=64
// Round 13: delete the prep stage. Round 12 confirmed the scan is back at
// 452us with the head fused, but ~194us sits OUTSIDE the scan (prep_x's 201MB
// in 32768 tiny blocks + prep_misc + gaps). Changes:
//  - weights converted fp32->bf16 in each block's PROLOGUE (once-only; each
//    block's threads collectively read the full matrices anyway). Consumer
//    computes gamma-scaling, S1/S2 row sums (frag partials + shfl over the 4
//    q-lanes) and fused biases in-prologue. prep_misc deleted.
//  - x converted by the producer itself, 8 groups ahead, in group-boundary
//    slack: prologue converts groups 0-7; each boundary stores group kk+8
//    (fp32 regs loaded one group earlier -> no vmcnt stall at convert) and
//    loads fp32 for kk+9. store->ldg8 gap = 6 boundaries, and the every-4th-
//    group release (vmcnt(0)+s_barrier, all waves) provides cross-thread
//    visibility. Steady-state ldg8 xf prefetch stays a PURE load (round-10
//    lesson). prep_x deleted.
//  - head tail reads fc1W/fcoW raw (transposed indexing, once-only, L2).
// Launches: zero_flags (flags may be re-poisoned) + scan_pair. 
// ---------------------------------------------------------------------------

typedef __attribute__((ext_vector_type(8))) short bf16x8;
typedef __attribute__((ext_vector_type(4))) float f32x4;
typedef __attribute__((ext_vector_type(4))) int i32x4;
typedef unsigned short u16;
typedef unsigned int u32;

#define TT 512
#define HSTR 136           // hbuf row stride in u16: 272B = 17*16 -> aligned b128

__device__ __forceinline__ u16 f2bf(float f) {
  u32 u = __builtin_bit_cast(u32, f);
  u += 0x7fffu + ((u >> 16) & 1u);
  return (u16)(u >> 16);
}
__device__ __forceinline__ float bf2f(u16 h) {
  return __builtin_bit_cast(float, (u32)h << 16);
}
__device__ __forceinline__ u32 packbf2(float a, float b) {
  return (u32)f2bf(a) | ((u32)f2bf(b) << 16);
}
__device__ __forceinline__ bf16x8 ldg8(const u16* p) {
  return __builtin_bit_cast(bf16x8, *(const i32x4*)p);
}
// load 8 fp32 and convert to a bf16x8 frag (prologue-only use)
__device__ __forceinline__ bf16x8 ldx8(const float* p) {
  const float4 v0 = *(const float4*)p;
  const float4 v1 = *(const float4*)(p + 4);
  i32x4 r;
  r[0] = (int)packbf2(v0.x, v0.y);
  r[1] = (int)packbf2(v0.z, v0.w);
  r[2] = (int)packbf2(v1.x, v1.y);
  r[3] = (int)packbf2(v1.z, v1.w);
  return __builtin_bit_cast(bf16x8, r);
}
__device__ __forceinline__ float frcp(float x) { return __builtin_amdgcn_rcpf(x); }
__device__ __forceinline__ float sigm(float x) { return frcp(1.f + __expf(-x)); }
__device__ __forceinline__ float tanh_f(float x) {
  return 1.f - 2.f * frcp(__expf(2.f * x) + 1.f);
}
// barrier draining LDS only (vmcnt stays outstanding: x-frag prefetch + lout
// stores stay off the critical path). 0xC07F = vmcnt(63) expcnt(7) lgkm(0)
__device__ __forceinline__ void scan_barrier() {
  __asm__ volatile("" ::: "memory");
  __builtin_amdgcn_s_waitcnt(0xC07F);
  __builtin_amdgcn_s_barrier();
  __asm__ volatile("" ::: "memory");
}
// accumulate sum / sum-of-squares of the 8 bf16 elements of a frag
__device__ __forceinline__ void acc_stats(bf16x8 v, float& s1, float& s2) {
#pragma unroll
  for (int j = 0; j < 8; j++) {
    float f = bf2f((u16)v[j]);
    s1 += f;
    s2 = __builtin_fmaf(f, f, s2);
  }
}

__global__ void zero_flags(u32* __restrict__ f) { f[threadIdx.x] = 0; }

// ---------------------------------------------------------------------------
// Fused producer/consumer scan. 256 blocks x 512 thr. All weight prep inlined
// into block prologues; x converted by the producer 8 groups ahead.
// Pair mapping: pid=16k+j (j<8) -> producer grp 8k+j; pid=16k+8+j -> consumer
// grp 8k+j. Both on XCD j under round-robin -> flag+lout traffic L2-local.
// ---------------------------------------------------------------------------
__global__ __launch_bounds__(512, 2) void scan_pair(
    const float* __restrict__ x,     // [B][T][128] fp32 (LSTM input)
    const float* __restrict__ whhl,  // [512][128] fp32
    const float* __restrict__ wihl,  // [512][128] fp32
    const float* __restrict__ bihl, const float* __restrict__ bhhl,
    const float* __restrict__ whhg,  // [384][128] fp32
    const float* __restrict__ wihg,  // [384][128] fp32
    const float* __restrict__ gbih, const float* __restrict__ gbhh,
    const float* __restrict__ lnLg, const float* __restrict__ lnLb,
    u16* __restrict__ xb,            // [B][T][128] bf16 (self-converted x)
    u16* __restrict__ lout,          // [B][T][128] bf16 raw lstm h
    u32* __restrict__ flags,         // [128] progress (steps completed)
    const float* __restrict__ lnGg, const float* __restrict__ lnGb,
    const float* __restrict__ fc1W, const float* __restrict__ fc1b,
    const float* __restrict__ lnFg, const float* __restrict__ lnFb,
    const float* __restrict__ fcoW, const float* __restrict__ fcob,
    float* __restrict__ out) {       // [512][64] fp32
  const int tid = threadIdx.x;
  const int w = tid >> 6, l = tid & 63;
  const int hc = l & 15, q = l >> 4;
  const int col = w * 16 + hc;
  const int pid = blockIdx.x;
  const int grp = ((pid >> 4) << 3) | (pid & 7);
  const int role = (pid >> 3) & 1;
  const int b0 = grp * 4;
  const int mrow = q * 4;
  const int hbase = hc * HSTR + q * 8;

  __shared__ __align__(16) u16 hb0[16 * HSTR];
  __shared__ __align__(16) u16 hb1[16 * HSTR];
  __shared__ float2 stats[2][16];   // (mu, rs) per group row; double-buffered
  __shared__ float hl[4][128];      // consumer tail: h_last / LN'd y
  __shared__ float zl[4][160];      // consumer tail: fc1 out / LN'd z

  for (int i = tid; i < 16 * HSTR; i += 512) { hb0[i] = 0; hb1[i] = 0; }

  if (role == 0) {
    // ------------------------- LSTM producer -------------------------
    // weight prologue: fp32 -> bf16 frags (once)
    bf16x8 wfh[4][4], wfx[4][4];
#pragma unroll
    for (int g = 0; g < 4; g++)
#pragma unroll
      for (int k0 = 0; k0 < 4; k0++) {
        wfh[g][k0] = ldx8(&whhl[(g * 128 + col) * 128 + k0 * 32 + q * 8]);
        wfx[g][k0] = ldx8(&wihl[(g * 128 + col) * 128 + k0 * 32 + q * 8]);
      }
    float bsl[4];
#pragma unroll
    for (int g = 0; g < 4; g++) bsl[g] = bihl[g * 128 + col] + bhhl[g * 128 + col];

    // x conversion prologue: groups 0..7 of this block's 4 batches.
    // thread -> batch j = tid>>7, elems (tid&127)*4 .. +3 of each 512-elem group
    const u32 cb = (u32)(b0 + (tid >> 7)) * (TT * 128) + (u32)(tid & 127) * 4;
#pragma unroll
    for (int g8 = 0; g8 < 8; g8++) {
      float4 v = *(const float4*)(x + cb + g8 * 512);
      *(uint2*)(xb + cb + g8 * 512) = make_uint2(packbf2(v.x, v.y), packbf2(v.z, v.w));
    }
    float4 xs = *(const float4*)(x + cb + 8 * 512);  // fp32 of group 8
    u32 xsoff = cb + 8 * 512;                        // store target for xs
    // all threads' xb stores must be visible before any thread's ldg8:
    __builtin_amdgcn_s_waitcnt(0x0070);
    __builtin_amdgcn_s_barrier();

    float c = 0.f;
    u32 loff = (u32)(b0 + q) * (TT * 128) + col;
    const u32 xbase = (u32)(b0 + (hc >> 2)) * (TT * 128) + (u32)(hc & 3) * 128 + q * 8;

    f32x4 axA[4], axB[4];
    bf16x8 xf[4];
    {
      bf16x8 f0[4];
#pragma unroll
      for (int k0 = 0; k0 < 4; k0++) f0[k0] = ldg8(&xb[xbase + k0 * 32]);
#pragma unroll
      for (int g = 0; g < 4; g++) axA[g] = (f32x4){0.f, 0.f, 0.f, 0.f};
#pragma unroll
      for (int k0 = 0; k0 < 4; k0++)
#pragma unroll
        for (int g = 0; g < 4; g++)
          axA[g] = __builtin_amdgcn_mfma_f32_16x16x32_bf16(f0[k0], wfx[g][k0], axA[g], 0, 0, 0);
    }
#pragma unroll
    for (int k0 = 0; k0 < 4; k0++) xf[k0] = ldg8(&xb[xbase + 512 + k0 * 32]);
    u32 xload = xbase + 1024;
    scan_barrier();

    auto step = [&](int s, f32x4 (&axc)[4], f32x4 (&axn)[4],
                    const u16* hrd, u16* hwr) {
      bf16x8 af[4];
#pragma unroll
      for (int k0 = 0; k0 < 4; k0++) af[k0] = ldg8(&hrd[hbase + k0 * 32]);
      f32x4 ah[4];
#pragma unroll
      for (int g = 0; g < 4; g++) ah[g] = (f32x4){0.f, 0.f, 0.f, 0.f};
#pragma unroll
      for (int k0 = 0; k0 < 4; k0++)
#pragma unroll
        for (int g = 0; g < 4; g++)
          ah[g] = __builtin_amdgcn_mfma_f32_16x16x32_bf16(af[k0], wfh[g][k0], ah[g], 0, 0, 0);
      float pi = ah[0][0] + axc[0][s] + bsl[0];
      float pf = ah[1][0] + axc[1][s] + bsl[1];
      float pg = ah[2][0] + axc[2][s] + bsl[2];
      float po = ah[3][0] + axc[3][s] + bsl[3];
      c = sigm(pf) * c + sigm(pi) * tanh_f(pg);
      float h = sigm(po) * tanh_f(c);
      u16 hv = f2bf(h);
      hwr[mrow * HSTR + col] = hv;
      lout[loff] = hv;
      loff += 128;
#pragma unroll
      for (int g = 0; g < 4; g++)
        axn[g] = __builtin_amdgcn_mfma_f32_16x16x32_bf16(xf[s], wfx[g][s], axn[g], 0, 0, 0);
      scan_barrier();
    };

    auto group = [&](f32x4 (&axc)[4], f32x4 (&axn)[4], u32 rel, int kk) {
#pragma unroll
      for (int g = 0; g < 4; g++) axn[g] = (f32x4){0.f, 0.f, 0.f, 0.f};
      step(0, axc, axn, hb0, hb1);
      step(1, axc, axn, hb1, hb0);
      step(2, axc, axn, hb0, hb1);
      step(3, axc, axn, hb1, hb0);
      if (rel) {
        // drain all waves' lout+xb stores (0x0070 = vmcnt(0) exp(7) lgkm(0));
        // everything issued below stays async past the release.
        __builtin_amdgcn_s_waitcnt(0x0070);
        __builtin_amdgcn_s_barrier();
        if (tid == 0)
          __hip_atomic_store(flags + grp, rel, __ATOMIC_RELEASE, __HIP_MEMORY_SCOPE_AGENT);
      }
      // x self-conversion: store group kk+8 (xs loaded at end of kk-1 -> no
      // vmcnt stall here), then load fp32 for group kk+9 (pure async load).
      if (kk + 8 <= 127)
        *(uint2*)(xb + xsoff) = make_uint2(packbf2(xs.x, xs.y), packbf2(xs.z, xs.w));
      if (kk + 9 <= 127)
        xs = *(const float4*)(x + xsoff + 512);
      xsoff += 512;
      // xf prefetch for group kk+2 (pure ldg8; written at end of kk-6, with a
      // release [vmcnt(0)+barrier] in every 6-boundary window -> visible)
#pragma unroll
      for (int k0 = 0; k0 < 4; k0++) xf[k0] = ldg8(&xb[xload + k0 * 32]);
      xload += 512;
    };

#pragma unroll 1
    for (int tg = 0; tg < TT; tg += 8) {
      const int kk = tg >> 2;
      group(axA, axB, 0u, kk);
      group(axB, axA, (tg & 8) ? (u32)(tg + 8) : 0u, kk + 1);
    }
    __builtin_amdgcn_s_waitcnt(0x0070);
    __builtin_amdgcn_s_barrier();
    if (tid == 0)
      __hip_atomic_store(flags + grp, (u32)TT, __ATOMIC_RELEASE, __HIP_MEMORY_SCOPE_AGENT);

  } else {
    // ------------------------- GRU consumer -------------------------
    // weight prologue: whh plain convert; wih scaled by LN gamma; S1 (sum of
    // scaled row) and S2 (sum of w*beta) via frag partials + shfl over q-lanes.
    bf16x8 wfh[3][4], wfx[3][4];
    float s1g[3], s2c[3];
#pragma unroll
    for (int g = 0; g < 3; g++) {
      float p1 = 0.f, p2 = 0.f;
#pragma unroll
      for (int k0 = 0; k0 < 4; k0++) {
        const int rbase = (g * 128 + col) * 128 + k0 * 32 + q * 8;
        const int sbase = k0 * 32 + q * 8;
        wfh[g][k0] = ldx8(&whhg[rbase]);
        const float4 a0 = *(const float4*)(wihg + rbase);
        const float4 a1 = *(const float4*)(wihg + rbase + 4);
        const float4 g0 = *(const float4*)(lnLg + sbase);
        const float4 g1 = *(const float4*)(lnLg + sbase + 4);
        const float4 e0 = *(const float4*)(lnLb + sbase);
        const float4 e1 = *(const float4*)(lnLb + sbase + 4);
        const float s0 = a0.x * g0.x, s1_ = a0.y * g0.y, s2_ = a0.z * g0.z, s3 = a0.w * g0.w;
        const float s4 = a1.x * g1.x, s5 = a1.y * g1.y, s6 = a1.z * g1.z, s7 = a1.w * g1.w;
        i32x4 r;
        r[0] = (int)packbf2(s0, s1_);
        r[1] = (int)packbf2(s2_, s3);
        r[2] = (int)packbf2(s4, s5);
        r[3] = (int)packbf2(s6, s7);
        wfx[g][k0] = __builtin_bit_cast(bf16x8, r);
        p1 += (s0 + s1_) + (s2_ + s3) + (s4 + s5) + (s6 + s7);
        p2 += a0.x * e0.x + a0.y * e0.y + a0.z * e0.z + a0.w * e0.w +
              a1.x * e1.x + a1.y * e1.y + a1.z * e1.z + a1.w * e1.w;
      }
      p1 += __shfl_xor(p1, 16); p1 += __shfl_xor(p1, 32);
      p2 += __shfl_xor(p2, 16); p2 += __shfl_xor(p2, 32);
      s1g[g] = p1; s2c[g] = p2;
    }
    // S2 (beta term of folded LN) merges into the x-side gate biases
    const float brz = gbih[col] + gbhh[col] + s2c[0];
    const float bzz = gbih[128 + col] + gbhh[128 + col] + s2c[1];
    const float bnx = gbih[256 + col] + s2c[2];
    const float bnh = gbhh[256 + col];

    float hp = 0.f;
    const u32 xbase = (u32)(b0 + (hc >> 2)) * (TT * 128) + (u32)(hc & 3) * 128 + q * 8;
    float s1a = 0.f, s2a = 0.f;
    u32 seen = 0;

    // wait for first 8 timesteps of lout (first release value is 16)
    while (seen < 8) {
      seen = __hip_atomic_load(flags + grp, __ATOMIC_ACQUIRE, __HIP_MEMORY_SCOPE_AGENT);
      if (seen < 8) __builtin_amdgcn_s_sleep(8);
    }

    f32x4 axA[3], axB[3];
    bf16x8 xf[4];
    {
      bf16x8 f0[4];
#pragma unroll
      for (int k0 = 0; k0 < 4; k0++) f0[k0] = ldg8(&lout[xbase + k0 * 32]);
#pragma unroll
      for (int g = 0; g < 3; g++) axA[g] = (f32x4){0.f, 0.f, 0.f, 0.f};
#pragma unroll
      for (int k0 = 0; k0 < 4; k0++)
#pragma unroll
        for (int g = 0; g < 3; g++)
          axA[g] = __builtin_amdgcn_mfma_f32_16x16x32_bf16(f0[k0], wfx[g][k0], axA[g], 0, 0, 0);
      // stats(group 0) from the prologue frags
      float a1 = 0.f, a2 = 0.f;
#pragma unroll
      for (int k0 = 0; k0 < 4; k0++) acc_stats(f0[k0], a1, a2);
      a1 += __shfl_xor(a1, 16); a1 += __shfl_xor(a1, 32);
      a2 += __shfl_xor(a2, 16); a2 += __shfl_xor(a2, 32);
      float mu = a1 * 0.0078125f;
      float var = a2 * 0.0078125f - mu * mu;
      float rsv = rsqrtf(var + 1e-5f);
      if (w == 0 && q == 0) stats[0][hc] = make_float2(mu, rsv);
    }
#pragma unroll
    for (int k0 = 0; k0 < 4; k0++) xf[k0] = ldg8(&lout[xbase + 512 + k0 * 32]);
    u32 xload = xbase + 1024;
    scan_barrier();

    auto step = [&](int s, f32x4 (&axc)[3], f32x4 (&axn)[3],
                    const u16* hrd, u16* hwr, int rdslot) {
      bf16x8 af[4];
#pragma unroll
      for (int k0 = 0; k0 < 4; k0++) af[k0] = ldg8(&hrd[hbase + k0 * 32]);
      f32x4 ah[3];
#pragma unroll
      for (int g = 0; g < 3; g++) ah[g] = (f32x4){0.f, 0.f, 0.f, 0.f};
#pragma unroll
      for (int k0 = 0; k0 < 4; k0++)
#pragma unroll
        for (int g = 0; g < 3; g++)
          ah[g] = __builtin_amdgcn_mfma_f32_16x16x32_bf16(af[k0], wfh[g][k0], ah[g], 0, 0, 0);
      // algebraic-LN fixup (runs in parallel with the MFMA chain above)
      const float2 st = stats[rdslot][4 * q + s];
      const float rsu = st.x * st.y;  // mu*rs
      float ax0 = st.y * axc[0][s] - rsu * s1g[0];
      float ax1 = st.y * axc[1][s] - rsu * s1g[1];
      float ax2 = st.y * axc[2][s] - rsu * s1g[2];
      float rr = sigm(ax0 + ah[0][0] + brz);
      float zz = sigm(ax1 + ah[1][0] + bzz);
      float nn = tanh_f(ax2 + bnx + rr * (ah[2][0] + bnh));
      hp = nn + zz * (hp - nn);
      hwr[mrow * HSTR + col] = f2bf(hp);
#pragma unroll
      for (int g = 0; g < 3; g++)
        axn[g] = __builtin_amdgcn_mfma_f32_16x16x32_bf16(xf[s], wfx[g][s], axn[g], 0, 0, 0);
      // accumulate next group's row stats from the frag just consumed
      acc_stats(xf[s], s1a, s2a);
      if (s == 3) {
        float t1 = s1a + __shfl_xor(s1a, 16); t1 += __shfl_xor(t1, 32);
        float t2 = s2a + __shfl_xor(s2a, 16); t2 += __shfl_xor(t2, 32);
        float mu = t1 * 0.0078125f;
        float var = t2 * 0.0078125f - mu * mu;
        float rsv = rsqrtf(var + 1e-5f);
        if (w == 0 && q == 0) stats[rdslot ^ 1][hc] = make_float2(mu, rsv);
        s1a = 0.f; s2a = 0.f;
      }
      scan_barrier();
    };

    auto group = [&](f32x4 (&axc)[3], f32x4 (&axn)[3], int rdslot) {
#pragma unroll
      for (int g = 0; g < 3; g++) axn[g] = (f32x4){0.f, 0.f, 0.f, 0.f};
      step(0, axc, axn, hb0, hb1, rdslot);
      step(1, axc, axn, hb1, hb0, rdslot);
      step(2, axc, axn, hb0, hb1, rdslot);
      step(3, axc, axn, hb1, hb0, rdslot);
#pragma unroll
      for (int k0 = 0; k0 < 4; k0++) xf[k0] = ldg8(&lout[xload + k0 * 32]);
      xload += 512;
    };

#pragma unroll 1
    for (int tg = 0; tg < TT; tg += 8) {
      u32 need = (u32)(tg + 16) > (u32)TT ? (u32)TT : (u32)(tg + 16);
      if (seen < need) {
        do {
          seen = __hip_atomic_load(flags + grp, __ATOMIC_ACQUIRE, __HIP_MEMORY_SCOPE_AGENT);
          if (seen < need) __builtin_amdgcn_s_sleep(8);
        } while (seen < need);
      }
      group(axA, axB, (tg >> 2) & 1);
      group(axB, axA, ((tg >> 2) + 1) & 1);
    }

    // -------------------- fused head (runs once) --------------------
    hl[q][col] = hp;
    __syncthreads();
    if (tid < 256) {             // LN(gru) + relu, one wave per batch row
      const int u = tid >> 6, ln = tid & 63;
      float a0 = hl[u][ln], a1 = hl[u][ln + 64];
      float s1 = a0 + a1, s2 = a0 * a0 + a1 * a1;
#pragma unroll
      for (int m = 1; m < 64; m <<= 1) { s1 += __shfl_xor(s1, m); s2 += __shfl_xor(s2, m); }
      float mean = s1 * 0.0078125f;
      float var = s2 * 0.0078125f - mean * mean;
      float rs = rsqrtf(var + 1e-5f);
      hl[u][ln]      = fmaxf((a0 - mean) * rs * lnGg[ln] + lnGb[ln], 0.f);
      hl[u][ln + 64] = fmaxf((a1 - mean) * rs * lnGg[ln + 64] + lnGb[ln + 64], 0.f);
    }
    __syncthreads();
    for (int idx = tid; idx < 640; idx += 512) {   // fc1: 4 batches x 160
      const int u = idx / 160, f = idx - u * 160;
      float z = fc1b[f];
      for (int g = 0; g < 128; g++) z = __builtin_fmaf(hl[u][g], fc1W[f * 128 + g], z);
      zl[u][f] = z;
    }
    __syncthreads();
    if (tid < 256) {             // LN(fc1) + relu (in-place: 1 thread per elem)
      const int u = tid >> 6, ln = tid & 63;
      float v0 = zl[u][ln], v1 = zl[u][ln + 64];
      float v2 = (ln < 32) ? zl[u][ln + 128] : 0.f;
      float s1 = v0 + v1 + v2, s2 = v0 * v0 + v1 * v1 + v2 * v2;
#pragma unroll
      for (int m = 1; m < 64; m <<= 1) { s1 += __shfl_xor(s1, m); s2 += __shfl_xor(s2, m); }
      float mean = s1 * (1.f / 160.f);
      float var = s2 * (1.f / 160.f) - mean * mean;
      float rs = rsqrtf(var + 1e-5f);
      zl[u][ln]      = fmaxf((v0 - mean) * rs * lnFg[ln] + lnFb[ln], 0.f);
      zl[u][ln + 64] = fmaxf((v1 - mean) * rs * lnFg[ln + 64] + lnFb[ln + 64], 0.f);
      if (ln < 32)
        zl[u][ln + 128] = fmaxf((v2 - mean) * rs * lnFg[ln + 128] + lnFb[ln + 128], 0.f);
    }
    __syncthreads();
    if (tid < 256) {             // fco: 4 batches x 64
      const int u = tid >> 6, cc = tid & 63;
      float o = fcob[cc];
      for (int f = 0; f < 160; f++) o = __builtin_fmaf(zl[u][f], fcoW[cc * 160 + f], o);
      out[(size_t)(b0 + u) * 64 + cc] = o;
    }
  }
}

// ---------------------------------------------------------------------------
// workspace layout (bytes): xbf then lout — the scans' 1-group-ahead frag
// prefetch overruns by <2KB into the adjacent region harmlessly. flags sits
// 64KB past lout (clear of the consumer's harmless read-overrun).
// ---------------------------------------------------------------------------
static constexpr size_t OFF_XBF   = 0;                          // 67,108,864
static constexpr size_t OFF_LOUT  = 67108864;                   // 67,108,864
static constexpr size_t OFF_FLAGS = OFF_LOUT + 67108864 + 65536; // 512

extern "C" void kernel_launch(void* const* d_in, const int* in_sizes, int n_in,
                              void* d_out, int out_size, void* d_ws, size_t ws_size,
                              hipStream_t stream) {
  (void)in_sizes; (void)n_in; (void)out_size; (void)ws_size;
  const float* x    = (const float*)d_in[0];
  const float* lWih = (const float*)d_in[1];
  const float* lWhh = (const float*)d_in[2];
  const float* lbih = (const float*)d_in[3];
  const float* lbhh = (const float*)d_in[4];
  const float* gWih = (const float*)d_in[5];
  const float* gWhh = (const float*)d_in[6];
  const float* gbih = (const float*)d_in[7];
  const float* gbhh = (const float*)d_in[8];
  const float* lnLg = (const float*)d_in[9];
  const float* lnLb = (const float*)d_in[10];
  const float* lnGg = (const float*)d_in[11];
  const float* lnGb = (const float*)d_in[12];
  const float* fc1W = (const float*)d_in[13];
  const float* fc1b = (const float*)d_in[14];
  const float* lnFg = (const float*)d_in[15];
  const float* lnFb = (const float*)d_in[16];
  const float* fcoW = (const float*)d_in[17];
  const float* fcob = (const float*)d_in[18];

  char* ws = (char*)d_ws;
  u16* xbf   = (u16*)(ws + OFF_XBF);
  u16* lout  = (u16*)(ws + OFF_LOUT);
  u32* flags = (u32*)(ws + OFF_FLAGS);
  float* out = (float*)d_out;

  zero_flags<<<1, 128, 0, stream>>>(flags);
  scan_pair<<<256, 512, 0, stream>>>(x, lWhh, lWih, lbih, lbhh,
                                     gWhh, gWih, gbih, gbhh, lnLg, lnLb,
                                     xbf, lout, flags,
                                     lnGg, lnGb, fc1W, fc1b, lnFg, lnFb, fcoW, fcob,
                                     out);
}